// Round 12
// baseline (1952.735 us; speedup 1.0000x reference)
//
#include <hip/hip_runtime.h>

// FlowNetC correlation: B=8, C=128, H=128, W=256, PAD=4, MD=4, K=1, S1=S2=1
// out[b, dyi*9+dxi, h, w] = (1/128) * sum_c in1[b,c,h,w] * in2[b,c,h+dyi-4,w+dxi-4]
// (in2 zero outside bounds)
//
// R6 (4th submit; infra flake, never measured): depth-4 register pipeline
// (single change vs R5).
// R5 measured: 252us, VALUBusy 54% (vs R4 23% @ 247us), HBM 11%, VGPR 64,
// occupancy 40%, FETCH 141MB. Two different structures both ~250us with
// throughput pipes idle -> residual per-phase latency exposure. Depth-2 gave
// ~1 phase (~100 own-cycles) of slack; depth-4 gives 3 phases (~300), enough
// to cover L2/LLC latency even at ~3 resident waves/SIMD.
//  - wave = one (b, h, dy) output row: 64 lanes x 4 px; 9216 waves.
//  - 4 named in-flight channel sets (static regs, no dynamic indexing).
//  - per channel: 1 in1 float4 + 3 in2 float4 (w0-4, w0, w0+4), all aligned.
//  - edge lanes clamp; garbage feeds only epilogue-killed acc entries.
// XCD swizzle: 2304 blocks = 8 XCD x 288; XCD x owns exactly b = x.

#define NB 8
#define NC 128
#define NH 128
#define NW 256
#define ND 9
#define CH 32768                 // NH*NW floats = channel stride
#define SCALE (1.0f / 128.0f)

// snapshot set k, issue next loads into set k, FMA from snapshot
#define PHASE(k)                                                          \
    {                                                                     \
        const float a_[4]  = {A##k.x, A##k.y, A##k.z, A##k.w};            \
        const float bw[12] = {P##k.x, P##k.y, P##k.z, P##k.w,             \
                              Q##k.x, Q##k.y, Q##k.z, Q##k.w,             \
                              R##k.x, R##k.y, R##k.z, R##k.w};            \
        A##k = *(const float4*)(pa + oa);                                 \
        P##k = *(const float4*)(pb + ob0);                                \
        Q##k = *(const float4*)(pb + ob1);                                \
        R##k = *(const float4*)(pb + ob2);                                \
        oa += CH; ob0 += CH; ob1 += CH; ob2 += CH;                        \
        _Pragma("unroll")                                                 \
        for (int p = 0; p < 4; ++p)                                       \
            _Pragma("unroll")                                             \
            for (int d = 0; d < ND; ++d)                                  \
                acc[p][d] += a_[p] * bw[p + d];                           \
    }

// compute-only (tail): no further loads
#define PHASE_TAIL(k)                                                     \
    {                                                                     \
        const float a_[4]  = {A##k.x, A##k.y, A##k.z, A##k.w};            \
        const float bw[12] = {P##k.x, P##k.y, P##k.z, P##k.w,             \
                              Q##k.x, Q##k.y, Q##k.z, Q##k.w,             \
                              R##k.x, R##k.y, R##k.z, R##k.w};            \
        _Pragma("unroll")                                                 \
        for (int p = 0; p < 4; ++p)                                       \
            _Pragma("unroll")                                             \
            for (int d = 0; d < ND; ++d)                                  \
                acc[p][d] += a_[p] * bw[p + d];                           \
    }

#define LOAD_SET(k)                                                       \
    A##k = *(const float4*)(pa + oa);                                     \
    P##k = *(const float4*)(pb + ob0);                                    \
    Q##k = *(const float4*)(pb + ob1);                                    \
    R##k = *(const float4*)(pb + ob2);                                    \
    oa += CH; ob0 += CH; ob1 += CH; ob2 += CH;

__global__ __launch_bounds__(256, 4) void corr_kernel(
    const float* __restrict__ in1, const float* __restrict__ in2,
    float* __restrict__ out)
{
    const int bid = blockIdx.x;
    const int sid = (bid & 7) * 288 + (bid >> 3);     // XCD-contiguous
    const int id  = sid * 4 + (threadIdx.x >> 6);     // 0..9215
    const int g   = threadIdx.x & 63;

    const int dyi  = id % ND;
    const int rest = id / ND;        // 0..1023
    const int h    = rest & 127;
    const int b    = rest >> 7;

    const int w0 = g << 2;           // 4 px per lane: w0..w0+3
    const int hh = h + dyi - 4;      // in2 source row (wave-uniform)
    const bool valid = ((unsigned)hh < (unsigned)NH);
    const int hhc = valid ? hh : 0;

    const float* __restrict__ pa = in1 + (size_t)(b * NC * NH + h)   * NW;
    const float* __restrict__ pb = in2 + (size_t)(b * NC * NH + hhc) * NW;

    // 32-bit running offsets (max 127*32768+259 < 2^23)
    int oa  = w0;
    int ob0 = (g == 0)  ? 0  : (w0 - 4);   // bw[0..3]  = in2[w0-4..w0-1]
    int ob1 = w0;                          // bw[4..7]  = in2[w0..w0+3]
    int ob2 = (g == 63) ? w0 : (w0 + 4);   // bw[8..11] = in2[w0+4..w0+7]

    float acc[4][ND];
#pragma unroll
    for (int p = 0; p < 4; ++p)
#pragma unroll
        for (int d = 0; d < ND; ++d) acc[p][d] = 0.f;

    // prologue: load channels 0..3 into sets 0..3
    float4 A0, P0, Q0, R0;
    float4 A1, P1, Q1, R1;
    float4 A2, P2, Q2, R2;
    float4 A3, P3, Q3, R3;
    LOAD_SET(0)
    LOAD_SET(1)
    LOAD_SET(2)
    LOAD_SET(3)

    // main loop: 31 iters x 4 channels = ch 0..123 computed, ch 4..127 loaded
#pragma unroll 1
    for (int c = 0; c < NC - 4; c += 4) {
        PHASE(0)
        PHASE(1)
        PHASE(2)
        PHASE(3)
    }
    // tail: channels 124..127
    PHASE_TAIL(0)
    PHASE_TAIL(1)
    PHASE_TAIL(2)
    PHASE_TAIL(3)

    // epilogue: zero entries whose in2 sample is out of bounds, scale, store
    float* outp = out + ((size_t)(b * (ND * ND) + dyi * ND) * NH + h) * NW + w0;
#pragma unroll
    for (int d = 0; d < ND; ++d) {
        float v[4];
#pragma unroll
        for (int p = 0; p < 4; ++p) {
            const bool kill = (!valid) ||
                              (g == 0  && (p + d) < 4) ||   // w-sample < 0
                              (g == 63 && (p + d) > 7);     // w-sample > 255
            v[p] = kill ? 0.0f : acc[p][d] * SCALE;
        }
        float4 o4 = {v[0], v[1], v[2], v[3]};
        *(float4*)(outp + (size_t)d * CH) = o4;
    }
}

extern "C" void kernel_launch(void* const* d_in, const int* in_sizes, int n_in,
                              void* d_out, int out_size, void* d_ws, size_t ws_size,
                              hipStream_t stream) {
    const float* in1 = (const float*)d_in[0];
    const float* in2 = (const float*)d_in[1];
    float* out = (float*)d_out;
    corr_kernel<<<dim3(2304), dim3(256), 0, stream>>>(in1, in2, out);
}

// Round 16
// 545.169 us; speedup vs baseline: 3.5819x; 3.5819x over previous
//
#include <hip/hip_runtime.h>

// FlowNetC correlation: B=8, C=128, H=128, W=256, PAD=4, MD=4, K=1, S1=S2=1
// out[b, dyi*9+dxi, h, w] = (1/128) * sum_c in1[b,c,h,w] * in2[b,c,h+dyi-4,w+dxi-4]
//
// R7 (4th submit; infra flake, never measured): LDS h-strip blocking to kill
// the 9x row-redundancy through L2.
// Evidence: R4 (247us, VALUBusy 23%) vs R5 (252us, VALUBusy 54%) — identical
// time for 2x waves & 1.33x loads => not latency, not VALU, not lines. The
// invariant is 2.36 GB of 9x-redundant row reads through L2 (~9.4 TB/s eff).
// R6 (depth-4) spilled to scratch: 7 GB HBM traffic, 1805us — reverted.
//
// Block = 9 waves (576 thr) = (b, h-pair, w-half); wave wv = dy (0..8).
// Per channel: stage ONCE to LDS: 2 in1 half-rows (128 f) + 10 in2 half-rows
// (136 f with +-4 halo, padded to 256-f segments => full-wave global_load_lds,
// no exec-mask games). All 9 dy-waves consume from LDS. L2 traffic ~0.9 GB.
// Inner loop identical to proven R5 (36 FMA, same edge-kill logic).
// Double-buffered; one __syncthreads per channel (implicit vmcnt(0) drain).
// Grid 1024 = 8 XCD x 128 sid; XCD x owns exactly b = x.

#define NC 128
#define NH 128
#define NW 256
#define ND 9
#define CH 32768                 // NH*NW floats = channel stride
#define SCALE (1.0f / 128.0f)
#define BUFSZ 2816               // floats/buffer: [0,256) in1 2x128; [256,2816) in2 10x256

__device__ __forceinline__ void gl_lds16(const float* gp, float* lp) {
    __builtin_amdgcn_global_load_lds(
        (const __attribute__((address_space(1))) void*)gp,
        (__attribute__((address_space(3))) void*)lp, 16, 0, 0);
}

__global__ __launch_bounds__(576) void corr_kernel(
    const float* __restrict__ in1, const float* __restrict__ in2,
    float* __restrict__ out)
{
    __shared__ float lds[2][BUFSZ];

    const int bid = blockIdx.x;
    const int sid = (bid & 7) * 128 + (bid >> 3);   // XCD-contiguous
    const int wh  = sid & 1;                        // w-half
    const int hp  = (sid >> 1) & 63;                // h-pair
    const int b   = sid >> 7;

    const int wv  = threadIdx.x >> 6;               // wave = dy, 0..8
    const int g   = threadIdx.x & 63;
    const int r   = g >> 5;                         // sub-row 0/1
    const int L   = g & 31;

    const int h0    = hp << 1;
    const int wbase = wh << 7;                      // 0 or 128
    const int wl    = L << 2;                       // 0..124

    // ---- staging sources (channel 0); all advance by CH per channel ----
    // in2 segment wv: row clamp(h0-4+wv), floats [wbase-4, wbase+132) + pad.
    // Lane g sources 16B at clamped float index; edge garbage is epilogue-killed.
    const int row2 = min(max(h0 - 4 + wv, 0), NH - 1);
    const int lf2  = min(max(wbase - 4 + (g << 2), 0), NW - 4);
    const float* s2 = in2 + (size_t)(b * NC * NH + row2) * NW + lf2;

    // in2 segment 9 (row h0+5), staged by wave 1
    const int row9 = min(h0 + 5, NH - 1);
    const float* s9 = in2 + (size_t)(b * NC * NH + row9) * NW + lf2;

    // in1 both rows in one full-wave load: lane g -> row r, col wl
    // (dest float 4g = r*128 + wl exactly matches compute layout)
    const float* s1 = in1 + (size_t)(b * NC * NH + h0 + r) * NW + wbase + wl;

    // ---- channel-invariant LDS read offsets ----
    const int aoff = r * 128 + wl;                  // in1
    const int boff = 256 + (r + wv) * 256 + wl;     // in2 seg r+wv, halo origin

    float acc[4][ND];
#pragma unroll
    for (int p = 0; p < 4; ++p)
#pragma unroll
        for (int d = 0; d < ND; ++d) acc[p][d] = 0.f;

    // prologue: stage channel 0 into buffer 0
    gl_lds16(s2, &lds[0][256 + wv * 256]); s2 += CH;
    if (wv == 1) { gl_lds16(s9, &lds[0][256 + 9 * 256]); s9 += CH; }
    if (wv == 0) { gl_lds16(s1, &lds[0][0]);             s1 += CH; }
    __syncthreads();   // drains vmcnt(0)

#pragma unroll 1
    for (int c = 0; c < NC - 1; ++c) {
        const int cur = c & 1, nxt = cur ^ 1;
        // stage channel c+1 into the other buffer (async, drains at barrier)
        gl_lds16(s2, &lds[nxt][256 + wv * 256]); s2 += CH;
        if (wv == 1) { gl_lds16(s9, &lds[nxt][256 + 9 * 256]); s9 += CH; }
        if (wv == 0) { gl_lds16(s1, &lds[nxt][0]);             s1 += CH; }

        // compute channel c from current buffer
        const float4 A  = *(const float4*)&lds[cur][aoff];
        const float4 B0 = *(const float4*)&lds[cur][boff];
        const float4 B1 = *(const float4*)&lds[cur][boff + 4];
        const float4 B2 = *(const float4*)&lds[cur][boff + 8];
        const float a_[4]  = {A.x, A.y, A.z, A.w};
        const float bw[12] = {B0.x, B0.y, B0.z, B0.w,
                              B1.x, B1.y, B1.z, B1.w,
                              B2.x, B2.y, B2.z, B2.w};
#pragma unroll
        for (int p = 0; p < 4; ++p)
#pragma unroll
            for (int d = 0; d < ND; ++d)
                acc[p][d] += a_[p] * bw[p + d];
        __syncthreads();
    }
    {   // last channel (c = 127) from buffer 1, no further staging
        const float4 A  = *(const float4*)&lds[1][aoff];
        const float4 B0 = *(const float4*)&lds[1][boff];
        const float4 B1 = *(const float4*)&lds[1][boff + 4];
        const float4 B2 = *(const float4*)&lds[1][boff + 8];
        const float a_[4]  = {A.x, A.y, A.z, A.w};
        const float bw[12] = {B0.x, B0.y, B0.z, B0.w,
                              B1.x, B1.y, B1.z, B1.w,
                              B2.x, B2.y, B2.z, B2.w};
#pragma unroll
        for (int p = 0; p < 4; ++p)
#pragma unroll
            for (int d = 0; d < ND; ++d)
                acc[p][d] += a_[p] * bw[p + d];
    }

    // epilogue: kill out-of-bounds samples, scale, store
    const bool valid = ((unsigned)(h0 + r + wv - 4) < (unsigned)NH);
    float* outp = out + ((size_t)(b * (ND * ND) + wv * ND) * NH + (h0 + r)) * NW
                      + wbase + wl;
#pragma unroll
    for (int d = 0; d < ND; ++d) {
        float v[4];
#pragma unroll
        for (int p = 0; p < 4; ++p) {
            const bool kill = (!valid) ||
                              (wh == 0 && L == 0  && (p + d) < 4) ||  // w' < 0
                              (wh == 1 && L == 31 && (p + d) > 7);    // w' > 255
            v[p] = kill ? 0.0f : acc[p][d] * SCALE;
        }
        float4 o4 = {v[0], v[1], v[2], v[3]};
        *(float4*)(outp + (size_t)d * CH) = o4;
    }
}

extern "C" void kernel_launch(void* const* d_in, const int* in_sizes, int n_in,
                              void* d_out, int out_size, void* d_ws, size_t ws_size,
                              hipStream_t stream) {
    const float* in1 = (const float*)d_in[0];
    const float* in2 = (const float*)d_in[1];
    float* out = (float*)d_out;
    corr_kernel<<<dim3(1024), dim3(576), 0, stream>>>(in1, in2, out);
}